// Round 11
// baseline (270.363 us; speedup 1.0000x reference)
//
#include <hip/hip_runtime.h>
#include <hip/hip_fp16.h>
#include <stdint.h>

#define IN_F   4096
#define OUT_F  11008
#define TOKENS 2048
#define BM 256
#define BN 128
#define BK 64
#define NT (IN_F / BK)     // 64 K-tiles
#define NGROUP 32
#define OPW (OUT_F / 8)

typedef _Float16 f16;
typedef __attribute__((ext_vector_type(2))) _Float16 f16x2;
typedef __attribute__((ext_vector_type(8))) _Float16 f16x8;
typedef __attribute__((ext_vector_type(4))) float f32x4;

typedef __attribute__((address_space(3))) uint32_t lds_u32_t;
typedef const __attribute__((address_space(1))) uint32_t glb_u32_t;

#define SB0() __builtin_amdgcn_sched_barrier(0)

static __device__ __forceinline__ void gload_lds16(const void* g, void* l) {
    __builtin_amdgcn_global_load_lds((glb_u32_t*)g, (lds_u32_t*)l, 16, 0, 0);
}

// dequant one packed word -> 8 f16 in pair-permuted k-order (j, j+4)
static __device__ __forceinline__ f16x8 dequant8(uint32_t w, f16x2 sv, f16x2 zv) {
    uint32_t p0 = (w & 0x000F000Fu) | 0x64006400u;           // 1024 + nibble (exact f16)
    uint32_t p1 = ((w >> 4)  & 0x000F000Fu) | 0x64006400u;
    uint32_t p2 = ((w >> 8)  & 0x000F000Fu) | 0x64006400u;
    uint32_t p3 = ((w >> 12) & 0x000F000Fu) | 0x64006400u;
    f16x2 h0 = (__builtin_bit_cast(f16x2, p0) + zv) * sv;    // exact (w - z - 1), then * s
    f16x2 h1 = (__builtin_bit_cast(f16x2, p1) + zv) * sv;
    f16x2 h2 = (__builtin_bit_cast(f16x2, p2) + zv) * sv;
    f16x2 h3 = (__builtin_bit_cast(f16x2, p3) + zv) * sv;
    f16x8 o;
    o[0] = h0[0]; o[1] = h0[1];
    o[2] = h1[0]; o[3] = h1[1];
    o[4] = h2[0]; o[5] = h2[1];
    o[6] = h3[0]; o[7] = h3[1];
    return o;
}

// pre-pass: x f32 -> f16 with intra-octet pair permutation (0,4,1,5,2,6,3,7)
__global__ __launch_bounds__(256) void cvt_perm_kernel(const float* __restrict__ x,
                                                       f16* __restrict__ xws) {
    const int o = blockIdx.x * 256 + threadIdx.x;   // octet id
    const float4 a = *reinterpret_cast<const float4*>(x + (size_t)o * 8);
    const float4 b = *reinterpret_cast<const float4*>(x + (size_t)o * 8 + 4);
    f16x8 v;
    v[0] = (f16)a.x; v[1] = (f16)b.x; v[2] = (f16)a.y; v[3] = (f16)b.y;
    v[4] = (f16)a.z; v[5] = (f16)b.z; v[6] = (f16)a.w; v[7] = (f16)b.w;
    *reinterpret_cast<f16x8*>(xws + (size_t)o * 8) = v;
}

// One K-tile = 2 phases; reads RA/RB, stages A(T+1)->WA (gload) and B(T+1)->WB
// (dequant of WC). Loads words(T+2)->WN_. ODD tiles: mkc + next-group scale loads.
// vmcnt ledger (WS path): even tile issues [2gl][2gl][2Bw] -> vmcnt(2);
// odd adds [2sc] -> vmcnt(4). A-gloads always retired; newest loads stay in flight.
#define TILE_PH(RA, RB, WA, WB, WC, WN_, ODD, T)                                  \
  {                                                                               \
    const int tn1_ = ((T) + 1 < NT) ? (T) + 1 : NT - 1;                           \
    const int tn2_ = ((T) + 2 < NT) ? (T) + 2 : NT - 1;                           \
    /* ---------------- phase 1: acc rows 0-3 ---------------- */                 \
    if (ODD) { mkc(sv, zv, swN, zwN); }                                           \
    f16x8 af0[4], af1[4], bf[4];                                                  \
    _Pragma("unroll") for (int f = 0; f < 4; ++f)                                 \
      af0[f] = *reinterpret_cast<const f16x8*>(&(RA)[offA[f]]);                   \
    _Pragma("unroll") for (int f = 0; f < 4; ++f)                                 \
      bf[f] = *reinterpret_cast<const f16x8*>(&(RB)[offB[f]]);                    \
    *reinterpret_cast<f16x8*>(&(WB)[bo[0]]) = dequant8((WC)[0], sv, zv);          \
    if constexpr (USE_WS) {                                                       \
      gload_lds16(asrc[0] + (size_t)tn1_ * BK, &(WA)[aoff[0]]);                   \
      gload_lds16(asrc[1] + (size_t)tn1_ * BK, &(WA)[aoff[1]]);                   \
    } else { stage_A_f2((WA), tn1_, 0); }                                         \
    __builtin_amdgcn_s_barrier();                                                 \
    asm volatile("s_waitcnt lgkmcnt(0)" ::: "memory");                            \
    __builtin_amdgcn_s_setprio(1);                                                \
    _Pragma("unroll") for (int i = 0; i < 4; ++i)                                 \
      _Pragma("unroll") for (int j = 0; j < 4; ++j)                               \
        acc[i][j] = __builtin_amdgcn_mfma_f32_16x16x32_f16(af0[i], bf[j],         \
                                                           acc[i][j], 0, 0, 0);  \
    __builtin_amdgcn_s_setprio(0);                                                \
    __builtin_amdgcn_s_barrier();                                                 \
    /* ---------------- phase 2: acc rows 4-7 (B frags reused) ---------------- */\
    _Pragma("unroll") for (int f = 0; f < 4; ++f)                                 \
      af1[f] = *reinterpret_cast<const f16x8*>(&(RA)[offA[4 + f]]);               \
    *reinterpret_cast<f16x8*>(&(WB)[bo[1]]) = dequant8((WC)[1], sv, zv);          \
    if constexpr (USE_WS) {                                                       \
      gload_lds16(asrc[2] + (size_t)tn1_ * BK, &(WA)[aoff[2]]);                   \
      gload_lds16(asrc[3] + (size_t)tn1_ * BK, &(WA)[aoff[3]]);                   \
    } else { stage_A_f2((WA), tn1_, 1); }                                         \
    SB0();  /* pin A-gloads before the register loads for the vmcnt count */      \
    load_bw(tn2_, WN_);                                                           \
    if (ODD) {                                                                    \
      const int g_ = ((T) >> 1) + 2 < NGROUP ? ((T) >> 1) + 2 : NGROUP - 1;       \
      swN = qscales[(size_t)g_ * OUT_F + ncol];                                   \
      zwN = qzeros[(size_t)g_ * OPW + (ncol >> 3)];                               \
    }                                                                             \
    __builtin_amdgcn_s_barrier();                                                 \
    asm volatile("s_waitcnt lgkmcnt(0)" ::: "memory");                            \
    __builtin_amdgcn_s_setprio(1);                                                \
    _Pragma("unroll") for (int i = 0; i < 4; ++i)                                 \
      _Pragma("unroll") for (int j = 0; j < 4; ++j)                               \
        acc[4 + i][j] = __builtin_amdgcn_mfma_f32_16x16x32_f16(af1[i], bf[j],     \
                                                        acc[4 + i][j], 0, 0, 0); \
    __builtin_amdgcn_s_setprio(0);                                                \
    if constexpr (USE_WS) {                                                       \
      if (ODD) { asm volatile("s_waitcnt vmcnt(4)" ::: "memory"); }               \
      else     { asm volatile("s_waitcnt vmcnt(2)" ::: "memory"); }               \
    } else {                                                                      \
      asm volatile("s_waitcnt lgkmcnt(0)" ::: "memory");                          \
    }                                                                             \
    __builtin_amdgcn_s_barrier();                                                 \
  }

template<bool USE_WS>
__global__ __launch_bounds__(512, 2) void qgemm_kernel(
    const float*    __restrict__ x,
    const f16*      __restrict__ xws,
    const uint32_t* __restrict__ qweight,
    const uint32_t* __restrict__ qzeros,
    const int*      __restrict__ qscales,
    const float*    __restrict__ qscales_zeros,
    const float*    __restrict__ qscales_scales,
    float*          __restrict__ out)
{
    // chunk (row, slot) holds k-octet slot ^ (row&7) — conflict-free b128 phases.
    // heap buf = A tile (32 KB) + B tile (16 KB); 2 bufs = 96 KiB -> 1 block/CU.
    // Epilogue reuses heap as the cross-k-group reduction scratch (64 KB/round).
    __shared__ __align__(16) f16 heap[2][(BM + BN) * BK];

    f16* const Ab0 = &heap[0][0];
    f16* const Ab1 = &heap[1][0];
    f16* const Bb0 = &heap[0][BM * BK];
    f16* const Bb1 = &heap[1][BM * BK];

    const int tid  = threadIdx.x;
    const int lane = tid & 63;
    const int wid  = tid >> 6;      // 0..7
    const int kg   = wid >> 2;      // 0..1 : k-octet group (0-3 | 4-7)
    const int wm   = (wid >> 1) & 1;   // M half (128 rows)
    const int wn   = wid & 1;          // N half (64 cols)

    // XCD-exact: mt = bid&7 -> each XCD keeps one 256-row A-panel (2 MB f16) in L2
    const int mt = blockIdx.x & 7;
    const int nt = blockIdx.x >> 3;
    const int m0 = mt * BM;
    const int n0 = nt * BN;

    // ---------- B side: thread owns 1 column, octets og2, og2+1 ----------
    const int colb = tid & 127;
    const int og2  = (tid >> 7) << 1;    // 0,2,4,6
    const int ncol = n0 + colb;
    const float ssv   = qscales_scales[ncol];
    const float qzssv = qscales_zeros[ncol] * ssv;
    int bo[2];
    #pragma unroll
    for (int r = 0; r < 2; ++r)
        bo[r] = colb * BK + ((og2 + r) ^ (colb & 7)) * 8;
    const uint32_t* bptr = qweight + (size_t)og2 * OUT_F + ncol;

    // ---------- A side: 4 chunks/thread, linear LDS dest, swizzled source ----------
    const f16*   asrc[4];
    const float* fsrc[4];
    int aoff[4];
    #pragma unroll
    for (int i = 0; i < 4; ++i) {
        const int cid = i * 512 + tid;           // 0..2047 chunks (256 rows x 8)
        const int row = cid >> 3, slot = cid & 7;
        const int oct = slot ^ (row & 7);
        asrc[i] = xws + (size_t)(m0 + row) * IN_F + oct * 8;
        fsrc[i] = x   + (size_t)(m0 + row) * IN_F + oct * 8;
        aoff[i] = cid * 8;
    }

    // ---------- fragment read offsets (this wave's 32-k slice) ----------
    const int lr = lane & 15;
    const int lo = lane >> 4;
    const int koct = kg * 4 + lo;            // 0..7
    int offA[8], offB[4];
    #pragma unroll
    for (int f = 0; f < 8; ++f) {
        const int ra = wm * 128 + f * 16 + lr;
        offA[f] = ra * BK + (koct ^ (ra & 7)) * 8;
    }
    #pragma unroll
    for (int f = 0; f < 4; ++f) {
        const int rb = wn * 64 + f * 16 + lr;
        offB[f] = rb * BK + (koct ^ (rb & 7)) * 8;
    }

    f32x4 acc[8][4];
    #pragma unroll
    for (int i = 0; i < 8; ++i)
        #pragma unroll
        for (int j = 0; j < 4; ++j) {
            f32x4 z = {0.f, 0.f, 0.f, 0.f};
            acc[i][j] = z;
        }

    auto load_bw = [&](int t_, uint32_t* w) {
        const uint32_t* p = bptr + (size_t)t_ * 8 * OUT_F;
        w[0] = p[0];
        w[1] = p[OUT_F];
    };
    auto mkc = [&](f16x2& sv_, f16x2& zv_, int sw_, uint32_t zw_) {
        const float sf = (float)sw_ * ssv - qzssv;
        const int   z  = (int)((zw_ >> ((ncol & 7) * 4)) & 0xFu);
        const f16 sh = (f16)sf;
        const f16 zh = (f16)(float)(-(1025 + z));   // -(1024 + (z+1)), exact in f16
        sv_[0] = sh; sv_[1] = sh;
        zv_[0] = zh; zv_[1] = zh;
    };
    auto stage_A_f2 = [&](f16* Ab, int tt, int h) {
        #pragma unroll
        for (int i = 2 * h; i < 2 * h + 2; ++i) {
            const float* p = fsrc[i] + (size_t)tt * BK;
            const float4 v0 = *reinterpret_cast<const float4*>(p);
            const float4 v1 = *reinterpret_cast<const float4*>(p + 4);
            f16x8 v;
            v[0] = (f16)v0.x; v[1] = (f16)v1.x; v[2] = (f16)v0.y; v[3] = (f16)v1.y;
            v[4] = (f16)v0.z; v[5] = (f16)v1.z; v[6] = (f16)v0.w; v[7] = (f16)v1.w;
            *reinterpret_cast<f16x8*>(&Ab[aoff[i]]) = v;
        }
    };

    uint32_t wcur[2], wnxt[2];
    int swN; uint32_t zwN;
    f16x2 sv, zv;

    // ---------------- prologue: stage tile 0; prime words(1) + group-1 scales ----
    {
        uint32_t w0i[2];
        load_bw(0, w0i);
        const int      sw0 = qscales[ncol];
        const uint32_t zw0 = qzeros[ncol >> 3];
        if constexpr (USE_WS) {
            #pragma unroll
            for (int i = 0; i < 4; ++i)
                gload_lds16(asrc[i], &Ab0[aoff[i]]);
        } else {
            stage_A_f2(Ab0, 0, 0);
            stage_A_f2(Ab0, 0, 1);
        }
        load_bw(1, wcur);
        swN = qscales[OUT_F + ncol];           // group 1
        zwN = qzeros[OPW + (ncol >> 3)];
        mkc(sv, zv, sw0, zw0);                 // group 0 (tiles 0,1)
        *reinterpret_cast<f16x8*>(&Bb0[bo[0]]) = dequant8(w0i[0], sv, zv);
        *reinterpret_cast<f16x8*>(&Bb0[bo[1]]) = dequant8(w0i[1], sv, zv);
        asm volatile("s_waitcnt vmcnt(0)" ::: "memory");
        asm volatile("s_waitcnt lgkmcnt(0)" ::: "memory");
        __builtin_amdgcn_s_barrier();
    }

    // ---------------- main loop: 2 tiles (4 phases) per iteration ----------------
    for (int t = 0; t < NT; t += 2) {
        TILE_PH(Ab0, Bb0, Ab1, Bb1, wcur, wnxt, false, t)
        TILE_PH(Ab1, Bb1, Ab0, Bb0, wnxt, wcur, true,  t + 1)
    }

    // ---------------- cross-k-group reduction (2 rounds of 64 KB) ----------------
    f32x4* scratch = reinterpret_cast<f32x4*>(&heap[0][0]);
    const int wpos = wid & 3;
    #pragma unroll
    for (int h = 0; h < 2; ++h) {
        if (kg == 1) {
            #pragma unroll
            for (int i = 0; i < 4; ++i)
                #pragma unroll
                for (int j = 0; j < 4; ++j)
                    scratch[wpos * 1024 + (i * 4 + j) * 64 + lane] = acc[h * 4 + i][j];
        }
        __syncthreads();
        if (kg == 0) {
            #pragma unroll
            for (int i = 0; i < 4; ++i)
                #pragma unroll
                for (int j = 0; j < 4; ++j) {
                    const f32x4 p = scratch[wpos * 1024 + (i * 4 + j) * 64 + lane];
                    acc[h * 4 + i][j].x += p.x; acc[h * 4 + i][j].y += p.y;
                    acc[h * 4 + i][j].z += p.z; acc[h * 4 + i][j].w += p.w;
                }
        }
        __syncthreads();
    }

    // ---------------- epilogue: C/D layout col=lane&15, row=(lane>>4)*4+reg ------
    if (kg == 0) {
        const int orow = m0 + wm * 128 + lo * 4;
        const int ocol = n0 + wn * 64 + lr;
        #pragma unroll
        for (int i = 0; i < 8; ++i)
            #pragma unroll
            for (int j = 0; j < 4; ++j) {
                #pragma unroll
                for (int r = 0; r < 4; ++r)
                    out[(size_t)(orow + i * 16 + r) * OUT_F + ocol + j * 16] = acc[i][j][r];
            }
    }
}

extern "C" void kernel_launch(void* const* d_in, const int* in_sizes, int n_in,
                              void* d_out, int out_size, void* d_ws, size_t ws_size,
                              hipStream_t stream) {
    const float*    xp  = (const float*)d_in[0];
    const uint32_t* qw  = (const uint32_t*)d_in[1];
    const uint32_t* qz  = (const uint32_t*)d_in[2];
    const int*      qs  = (const int*)d_in[3];
    const float*    qsz = (const float*)d_in[4];
    const float*    qss = (const float*)d_in[5];
    // d_in[6] = g_idx: identity grouping (k/128), folded into the kernel.
    float* outp = (float*)d_out;

    const int grid = (TOKENS / BM) * (OUT_F / BN);   // 8 * 86 = 688
    const size_t need = (size_t)TOKENS * IN_F * sizeof(f16);   // 16 MiB

    if (ws_size >= need) {
        f16* xws = (f16*)d_ws;
        cvt_perm_kernel<<<(TOKENS * IN_F / 8) / 256, 256, 0, stream>>>(xp, xws);
        qgemm_kernel<true><<<grid, 512, 0, stream>>>(xp, xws, qw, qz, qs, qsz, qss, outp);
    } else {
        qgemm_kernel<false><<<grid, 512, 0, stream>>>(xp, (const f16*)nullptr,
                                                      qw, qz, qs, qsz, qss, outp);
    }
}

// Round 12
// 262.252 us; speedup vs baseline: 1.0309x; 1.0309x over previous
//
#include <hip/hip_runtime.h>
#include <hip/hip_fp16.h>
#include <stdint.h>

#define IN_F   4096
#define OUT_F  11008
#define TOKENS 2048
#define BM 128
#define BN 128
#define BK 64
#define NT (IN_F / BK)     // 64 K-tiles
#define NGROUP 32
#define OPW (OUT_F / 8)
#define BWPAD 136          // u32 per packed-B row (8 pad words -> bank stride 8)

typedef _Float16 f16;
typedef __attribute__((ext_vector_type(2))) _Float16 f16x2;
typedef __attribute__((ext_vector_type(8))) _Float16 f16x8;
typedef __attribute__((ext_vector_type(4))) float f32x4;

typedef __attribute__((address_space(3))) uint32_t lds_u32_t;
typedef const __attribute__((address_space(1))) uint32_t glb_u32_t;

#define SB0() __builtin_amdgcn_sched_barrier(0)

static __device__ __forceinline__ void gload_lds16(const void* g, void* l) {
    __builtin_amdgcn_global_load_lds((glb_u32_t*)g, (lds_u32_t*)l, 16, 0, 0);
}
static __device__ __forceinline__ void gload_lds4(const void* g, void* l) {
    __builtin_amdgcn_global_load_lds((glb_u32_t*)g, (lds_u32_t*)l, 4, 0, 0);
}

// dequant one packed word -> 8 f16 in pair-permuted k-order (j, j+4)
static __device__ __forceinline__ f16x8 dequant8(uint32_t w, f16x2 sv, f16x2 zv) {
    uint32_t p0 = (w & 0x000F000Fu) | 0x64006400u;           // 1024 + nibble (exact f16)
    uint32_t p1 = ((w >> 4)  & 0x000F000Fu) | 0x64006400u;
    uint32_t p2 = ((w >> 8)  & 0x000F000Fu) | 0x64006400u;
    uint32_t p3 = ((w >> 12) & 0x000F000Fu) | 0x64006400u;
    f16x2 h0 = (__builtin_bit_cast(f16x2, p0) + zv) * sv;    // exact (w - z - 1), then * s
    f16x2 h1 = (__builtin_bit_cast(f16x2, p1) + zv) * sv;
    f16x2 h2 = (__builtin_bit_cast(f16x2, p2) + zv) * sv;
    f16x2 h3 = (__builtin_bit_cast(f16x2, p3) + zv) * sv;
    f16x8 o;
    o[0] = h0[0]; o[1] = h0[1];
    o[2] = h1[0]; o[3] = h1[1];
    o[4] = h2[0]; o[5] = h2[1];
    o[6] = h3[0]; o[7] = h3[1];
    return o;
}

// pre-pass: x f32 -> f16 with intra-octet pair permutation (0,4,1,5,2,6,3,7)
__global__ __launch_bounds__(256) void cvt_perm_kernel(const float* __restrict__ x,
                                                       f16* __restrict__ xws) {
    const int o = blockIdx.x * 256 + threadIdx.x;   // octet id
    const float4 a = *reinterpret_cast<const float4*>(x + (size_t)o * 8);
    const float4 b = *reinterpret_cast<const float4*>(x + (size_t)o * 8 + 4);
    f16x8 v;
    v[0] = (f16)a.x; v[1] = (f16)b.x; v[2] = (f16)a.y; v[3] = (f16)b.y;
    v[4] = (f16)a.z; v[5] = (f16)b.z; v[6] = (f16)a.w; v[7] = (f16)b.w;
    *reinterpret_cast<f16x8*>(xws + (size_t)o * 8) = v;
}

template<bool USE_WS>
__global__ __launch_bounds__(512, 4) void qgemm_kernel(
    const float*    __restrict__ x,
    const f16*      __restrict__ xws,
    const uint32_t* __restrict__ qweight,
    const uint32_t* __restrict__ qzeros,
    const int*      __restrict__ qscales,
    const float*    __restrict__ qscales_zeros,
    const float*    __restrict__ qscales_scales,
    float*          __restrict__ out)
{
    // A: f16 [128 rows][8 chunks], chunk (row,slot) holds k-octet slot^(row&7).
    // Bw: PACKED int32 words [oct][col], row padded to 136 -> frag-read phases
    //     hit every bank <=2x (free). Scale tables: per-col f16x2 (s,s)/(z,z).
    __shared__ __align__(16) f16 Ash[2][BM * BK];            // 32 KiB
    __shared__ __align__(16) uint32_t Bw[2][8 * BWPAD];      // 8.5 KiB
    __shared__ uint32_t svtab[2][BN], zvtab[2][BN];          // 2 KiB   (total ~43.5K)

    const int tid  = threadIdx.x;
    const int lane = tid & 63;
    const int wid  = tid >> 6;      // 0..7
    const int kg   = wid >> 2;      // k-octet group (0: oct 0-3, 1: oct 4-7)
    const int wm   = (wid >> 1) & 1;
    const int wn   = wid & 1;

    // XCD map: bid&7 = XCD; mt = bid&15 -> XCD x hosts A-panels {x, x+8} in its L2
    const int mt = blockIdx.x & 15;
    const int nt = blockIdx.x >> 4;
    const int m0 = mt * BM;
    const int n0 = nt * BN;

    // ---- scale prep: every thread mirrors col cb (4x redundant -> uniform vmcnt)
    const int cb   = tid & 127;
    const int ncol = n0 + cb;
    const float ssv   = qscales_scales[ncol];
    const float qzssv = qscales_zeros[ncol] * ssv;

    // ---- A staging: 2 chunks/thread (rows r, r+64 share swizzle), linear dest
    const int arow = tid >> 3;
    const int aoct = (tid & 7) ^ (arow & 7);
    const f16*   asrc0 = xws + (size_t)(m0 + arow) * IN_F + aoct * 8;
    const float* fsrc0 = x   + (size_t)(m0 + arow) * IN_F + aoct * 8;
    const int aoff0 = tid * 8;
    const int aoff1 = (tid + 512) * 8;

    // ---- B packed staging: wave wid stages octet row wid, two 64-col halves
    const uint32_t* bsrc = qweight + (size_t)wid * OUT_F + n0 + lane;

    // ---- fragment read offsets
    const int lr = lane & 15;
    const int lo = lane >> 4;
    const int koct = kg * 4 + lo;            // 0..7
    int offA[4], bwoff[4], tco[4];
    #pragma unroll
    for (int f = 0; f < 4; ++f) {
        const int ra = wm * 64 + f * 16 + lr;
        offA[f]  = ra * BK + (koct ^ (ra & 7)) * 8;
        tco[f]   = wn * 64 + f * 16 + lr;    // B column of frag f
        bwoff[f] = koct * BWPAD + tco[f];
    }

    f32x4 acc[8][4];   // [2 unused rows folded: only 4 used] -- keep 4x4
    f32x4 (&accv)[8][4] = acc;
    (void)accv;
    #pragma unroll
    for (int i = 0; i < 4; ++i)
        #pragma unroll
        for (int j = 0; j < 4; ++j) {
            f32x4 z = {0.f, 0.f, 0.f, 0.f};
            acc[i][j] = z;
        }

    int swp; uint32_t zwp;                   // raw group words (register prefetch)
    f16x2 svu[4], zvu[4];                    // per-frag-col dequant consts (cached)

    auto load_sc = [&](int g_) {
        swp = qscales[(size_t)g_ * OUT_F + ncol];
        zwp = qzeros[(size_t)g_ * OPW + (ncol >> 3)];
    };
    auto tab_build = [&](int nb) {           // from swp/zwp (group already in regs)
        if (tid < 128) {
            const float sf = (float)swp * ssv - qzssv;
            const int   z  = (int)((zwp >> ((cb & 7) * 4)) & 0xFu);
            const f16 sh = (f16)sf;
            const f16 zh = (f16)(float)(-(1025 + z));
            f16x2 s2; s2[0] = sh; s2[1] = sh;
            f16x2 z2; z2[0] = zh; z2[1] = zh;
            svtab[nb][cb] = __builtin_bit_cast(uint32_t, s2);
            zvtab[nb][cb] = __builtin_bit_cast(uint32_t, z2);
        }
    };
    auto load_tab = [&](int gb) {
        #pragma unroll
        for (int f = 0; f < 4; ++f) {
            svu[f] = __builtin_bit_cast(f16x2, svtab[gb][tco[f]]);
            zvu[f] = __builtin_bit_cast(f16x2, zvtab[gb][tco[f]]);
        }
    };
    auto stage = [&](int buf, int t_) {
        if constexpr (USE_WS) {
            gload_lds16(asrc0 + (size_t)t_ * BK, &Ash[buf][aoff0]);
            gload_lds16(asrc0 + (size_t)t_ * BK + (size_t)64 * IN_F, &Ash[buf][aoff1]);
            gload_lds4(bsrc + (size_t)t_ * 8 * OUT_F,      &Bw[buf][wid * BWPAD + lane]);
            gload_lds4(bsrc + (size_t)t_ * 8 * OUT_F + 64, &Bw[buf][wid * BWPAD + 64 + lane]);
        } else {
            #pragma unroll
            for (int i = 0; i < 2; ++i) {
                const float* p = fsrc0 + (size_t)t_ * BK + (size_t)(64 * i) * IN_F;
                const float4 v0 = *reinterpret_cast<const float4*>(p);
                const float4 v1 = *reinterpret_cast<const float4*>(p + 4);
                f16x8 v;
                v[0] = (f16)v0.x; v[1] = (f16)v1.x; v[2] = (f16)v0.y; v[3] = (f16)v1.y;
                v[4] = (f16)v0.z; v[5] = (f16)v1.z; v[6] = (f16)v0.w; v[7] = (f16)v1.w;
                *reinterpret_cast<f16x8*>(&Ash[buf][i == 0 ? aoff0 : aoff1]) = v;
            }
            Bw[buf][wid * BWPAD + lane]      = bsrc[(size_t)t_ * 8 * OUT_F];
            Bw[buf][wid * BWPAD + 64 + lane] = bsrc[(size_t)t_ * 8 * OUT_F + 64];
        }
    };
    auto compute = [&](int buf) {
        f16x8 af[4];
        uint32_t w[4];
        #pragma unroll
        for (int f = 0; f < 4; ++f)
            af[f] = *reinterpret_cast<const f16x8*>(&Ash[buf][offA[f]]);
        #pragma unroll
        for (int f = 0; f < 4; ++f)
            w[f] = Bw[buf][bwoff[f]];
        __builtin_amdgcn_s_setprio(1);
        #pragma unroll
        for (int j = 0; j < 4; ++j) {
            const f16x8 bf = dequant8(w[j], svu[j], zvu[j]);
            #pragma unroll
            for (int i = 0; i < 4; ++i)
                acc[i][j] = __builtin_amdgcn_mfma_f32_16x16x32_f16(
                    af[i], bf, acc[i][j], 0, 0, 0);
        }
        __builtin_amdgcn_s_setprio(0);
    };

    // ---------------- prologue ----------------
    {
        load_sc(0);
        tab_build(0);                        // tab for group 0
        load_sc(1);                          // words for group 1 (built at tile 0)
        stage(0, 0);                         // tile 0: 4 gloads
        asm volatile("s_waitcnt vmcnt(0)" ::: "memory");
        asm volatile("s_waitcnt lgkmcnt(0)" ::: "memory");
        __builtin_amdgcn_s_barrier();
    }

    // ---------------- main loop: 2 tiles per iteration ----------------
    for (int t = 0; t < NT; t += 2) {
        const int g = t >> 1;
        // ---- even: compute tile t (buf0); stage t+1 (buf1); build tab g+1
        {
            stage(1, t + 1);                 // [4 gloads]
            tab_build((g + 1) & 1);          // consumes swp/zwp (compiler-counted wait)
            load_tab(g & 1);                 // cache group-g consts in regs
            compute(0);
            if constexpr (USE_WS)
                asm volatile("s_waitcnt vmcnt(0)" ::: "memory");   // exactly the 4
            asm volatile("s_waitcnt lgkmcnt(0)" ::: "memory");
            __builtin_amdgcn_s_barrier();
        }
        // ---- odd: compute tile t+1 (buf1); stage t+2 (buf0); prefetch sc g+2
        {
            const int tn2 = t + 2 < NT ? t + 2 : NT - 1;
            stage(0, tn2);                   // [4 gloads]
            SB0();                           // pin gloads before the sc reg loads
            load_sc(g + 2 < NGROUP ? g + 2 : NGROUP - 1);   // [2 reg loads]
            compute(1);
            if constexpr (USE_WS)
                asm volatile("s_waitcnt vmcnt(2)" ::: "memory");   // retire 4, keep sc
            asm volatile("s_waitcnt lgkmcnt(0)" ::: "memory");
            __builtin_amdgcn_s_barrier();
        }
    }

    // ---------------- cross-k-group reduction (4 rounds over Ash, 32 KiB) --------
    __syncthreads();
    f32x4* scratch = reinterpret_cast<f32x4*>(&Ash[0][0]);   // 2048 f32x4
    const int wpos = wid & 3;
    #pragma unroll
    for (int q = 0; q < 2; ++q) {            // acc rows {0,1} then {2,3}
        if (kg == 1) {
            #pragma unroll
            for (int di = 0; di < 2; ++di)
                #pragma unroll
                for (int j = 0; j < 4; ++j)
                    scratch[wpos * 512 + (di * 4 + j) * 64 + lane] = acc[2 * q + di][j];
        }
        __syncthreads();
        if (kg == 0) {
            #pragma unroll
            for (int di = 0; di < 2; ++di)
                #pragma unroll
                for (int j = 0; j < 4; ++j) {
                    const f32x4 p = scratch[wpos * 512 + (di * 4 + j) * 64 + lane];
                    acc[2 * q + di][j].x += p.x; acc[2 * q + di][j].y += p.y;
                    acc[2 * q + di][j].z += p.z; acc[2 * q + di][j].w += p.w;
                }
        }
        __syncthreads();
    }

    // ---------------- epilogue: C/D layout col=lane&15, row=(lane>>4)*4+reg ------
    if (kg == 0) {
        const int orow = m0 + wm * 64 + lo * 4;
        const int ocol = n0 + wn * 64 + lr;
        #pragma unroll
        for (int i = 0; i < 4; ++i)
            #pragma unroll
            for (int j = 0; j < 4; ++j) {
                #pragma unroll
                for (int r = 0; r < 4; ++r)
                    out[(size_t)(orow + i * 16 + r) * OUT_F + ocol + j * 16] = acc[i][j][r];
            }
    }
}

extern "C" void kernel_launch(void* const* d_in, const int* in_sizes, int n_in,
                              void* d_out, int out_size, void* d_ws, size_t ws_size,
                              hipStream_t stream) {
    const float*    xp  = (const float*)d_in[0];
    const uint32_t* qw  = (const uint32_t*)d_in[1];
    const uint32_t* qz  = (const uint32_t*)d_in[2];
    const int*      qs  = (const int*)d_in[3];
    const float*    qsz = (const float*)d_in[4];
    const float*    qss = (const float*)d_in[5];
    // d_in[6] = g_idx: identity grouping (k/128), folded into the kernel.
    float* outp = (float*)d_out;

    const int grid = (TOKENS / BM) * (OUT_F / BN);   // 16 * 86 = 1376
    const size_t need = (size_t)TOKENS * IN_F * sizeof(f16);   // 16 MiB

    if (ws_size >= need) {
        f16* xws = (f16*)d_ws;
        cvt_perm_kernel<<<(TOKENS * IN_F / 8) / 256, 256, 0, stream>>>(xp, xws);
        qgemm_kernel<true><<<grid, 512, 0, stream>>>(xp, xws, qw, qz, qs, qsz, qss, outp);
    } else {
        qgemm_kernel<false><<<grid, 512, 0, stream>>>(xp, (const f16*)nullptr,
                                                      qw, qz, qs, qsz, qss, outp);
    }
}